// Round 7
// baseline (344.078 us; speedup 1.0000x reference)
//
#include <hip/hip_runtime.h>
#include <math.h>
#include <stdint.h>

#define DIM_ 1024
#define HEADS_ 16
#define DK_ 64
#define B_ 2
#define L_ 2048
#define BH_ (B_*HEADS_)
#define M_ (B_*L_)

typedef __attribute__((ext_vector_type(4))) float f32x4;
typedef __attribute__((ext_vector_type(8))) short bf16x8;
typedef __attribute__((ext_vector_type(4))) short bf16x4;

#define QSCALE 0.18033688f   // 0.125 * log2(e): softmax in exp2 domain

static __device__ __forceinline__ short f2bf(float f) {
    uint32_t u = __builtin_bit_cast(uint32_t, f);
    u += 0x7fffu + ((u >> 16) & 1u);
    return (short)(u >> 16);
}
static __device__ __forceinline__ void gload16(const void* g, void* l) {
    __builtin_amdgcn_global_load_lds(
        (const __attribute__((address_space(1))) unsigned int*)g,
        (__attribute__((address_space(3))) unsigned int*)l, 16, 0, 0);
}

// ------------------------------------------------------------ prep: fp32 -> bf16
__global__ __launch_bounds__(256)
void cvt_bf16(const float* __restrict__ a, const float* __restrict__ b,
              short* __restrict__ ao, short* __restrict__ bo)
{
    const int id = blockIdx.x * 256 + threadIdx.x;
    const int nA = (M_ * DIM_) / 8;
    const float* src = (id < nA) ? a : b;
    short* dst = (id < nA) ? ao : bo;
    const int c = (id < nA) ? id : id - nA;
    const f32x4 v0 = *(const f32x4*)&src[(size_t)c * 8];
    const f32x4 v1 = *(const f32x4*)&src[(size_t)c * 8 + 4];
    bf16x8 o;
#pragma unroll
    for (int i = 0; i < 4; ++i) { o[i] = f2bf(v0[i]); o[4 + i] = f2bf(v1[i]); }
    *(bf16x8*)&dst[(size_t)c * 8] = o;
}

// ------------------------------------------------------------ prep: W[k][n] -> WT[n][k] bf16
__global__ __launch_bounds__(256)
void wtrans(const float* __restrict__ Wq, const float* __restrict__ Wk,
            const float* __restrict__ Wv, const float* __restrict__ Wo,
            short* __restrict__ WqT, short* __restrict__ WkT,
            short* __restrict__ WvT, short* __restrict__ WoT)
{
    const int z = blockIdx.z;
    const int K = (z == 3) ? 2 * DIM_ : DIM_;
    const int k0 = blockIdx.x * 64;
    if (k0 >= K) return;
    const int n0 = blockIdx.y * 64;
    const float* W = (z == 0) ? Wq : (z == 1) ? Wk : (z == 2) ? Wv : Wo;
    short* WT = (z == 0) ? WqT : (z == 1) ? WkT : (z == 2) ? WvT : WoT;

    __shared__ float ts[64][65];
    const int tid = threadIdx.x;
    {
        const int k = tid >> 2, noff = (tid & 3) * 16;
#pragma unroll
        for (int i = 0; i < 4; ++i)
            *(f32x4*)&ts[k][noff + i * 4] =
                *(const f32x4*)&W[(size_t)(k0 + k) * DIM_ + n0 + noff + i * 4];
    }
    __syncthreads();
    {
        const int n = tid >> 2, koff = (tid & 3) * 16;
#pragma unroll
        for (int c = 0; c < 2; ++c) {
            bf16x8 o;
#pragma unroll
            for (int i = 0; i < 8; ++i) o[i] = f2bf(ts[koff + c * 8 + i][n]);
            *(bf16x8*)&WT[(size_t)(n0 + n) * K + k0 + koff + c * 8] = o;
        }
    }
}

// ------------------------------------------------------------ QKV GEMM (MFMA, gload_lds, BK=64, XOR-swizzled LDS)
__global__ __launch_bounds__(256)
void qkv_mfma(const short* __restrict__ xoutb, const short* __restrict__ xctxb,
              const short* __restrict__ WqT, const short* __restrict__ WkT,
              const short* __restrict__ WvT,
              const float* __restrict__ bq, const float* __restrict__ bk,
              const float* __restrict__ bv,
              short* __restrict__ qh, short* __restrict__ kh, short* __restrict__ vT)
{
    const int z = blockIdx.z;
    const short* A  = (z == 0) ? xoutb : xctxb;
    const short* Bt = (z == 0) ? WqT : (z == 1) ? WkT : WvT;
    const float* bias = (z == 0) ? bq : (z == 1) ? bk : bv;

    const int flat = blockIdx.y * 8 + blockIdx.x;
    const int wgs = (flat & 7) * 32 + (flat >> 3);
    const int col0 = (wgs & 7) * 128;
    const int row0 = (wgs >> 3) * 128;
    const int tid = threadIdx.x;
    const int lane = tid & 63;
    const int w = tid >> 6;
    const int wm = (w >> 1) * 64, wn = (w & 1) * 64;
    const int l15 = lane & 15, g = lane >> 4;
    const int sub = lane >> 3, slt = lane & 7;

    __shared__ short As[128 * 64];
    __shared__ short Bs[128 * 64];

    const short* pA[4]; const short* pB[4]; short* ldsA[4]; short* ldsB[4];
#pragma unroll
    for (int i = 0; i < 4; ++i) {
        const int r = w * 32 + i * 8 + sub;
        const int sc = ((slt ^ (r & 7)) * 8);
        pA[i] = A  + (size_t)(row0 + r) * DIM_ + sc;
        pB[i] = Bt + (size_t)(col0 + r) * DIM_ + sc;
        ldsA[i] = &As[(w * 32 + i * 8) * 64];
        ldsB[i] = &Bs[(w * 32 + i * 8) * 64];
    }

    f32x4 acc[4][4];
#pragma unroll
    for (int mi = 0; mi < 4; ++mi)
#pragma unroll
        for (int ni = 0; ni < 4; ++ni) acc[mi][ni] = (f32x4)0.f;

    for (int k0 = 0; k0 < DIM_; k0 += 64) {
#pragma unroll
        for (int i = 0; i < 4; ++i) {
            gload16(pA[i] + k0, ldsA[i]);
            gload16(pB[i] + k0, ldsB[i]);
        }
        __syncthreads();
        bf16x8 af[4][2], bfr[4][2];
#pragma unroll
        for (int mi = 0; mi < 4; ++mi) {
            const int wa = wm + mi * 16 + l15;
#pragma unroll
            for (int ks = 0; ks < 2; ++ks)
                af[mi][ks] = *(const bf16x8*)&As[wa * 64 + (((ks * 4 + g) ^ (wa & 7)) * 8)];
        }
#pragma unroll
        for (int ni = 0; ni < 4; ++ni) {
            const int wb = wn + ni * 16 + l15;
#pragma unroll
            for (int ks = 0; ks < 2; ++ks)
                bfr[ni][ks] = *(const bf16x8*)&Bs[wb * 64 + (((ks * 4 + g) ^ (wb & 7)) * 8)];
        }
        __builtin_amdgcn_s_setprio(1);
#pragma unroll
        for (int mi = 0; mi < 4; ++mi)
#pragma unroll
            for (int ni = 0; ni < 4; ++ni)
#pragma unroll
                for (int ks = 0; ks < 2; ++ks)
                    acc[mi][ni] = __builtin_amdgcn_mfma_f32_16x16x32_bf16(af[mi][ks], bfr[ni][ks], acc[mi][ni], 0, 0, 0);
        __builtin_amdgcn_s_setprio(0);
        __syncthreads();
    }

#pragma unroll
    for (int ni = 0; ni < 4; ++ni) {
        const int col = col0 + wn + ni * 16 + l15;
        const int h = col >> 6, dk = col & 63;
        const float bb = bias[col];
#pragma unroll
        for (int mi = 0; mi < 4; ++mi) {
            const int rowb = row0 + wm + mi * 16 + g * 4;
            const int b = rowb >> 11;
            const int l = rowb & (L_ - 1);
            const int bh = b * 16 + h;
            if (z == 2) {
                bf16x4 o;
#pragma unroll
                for (int r = 0; r < 4; ++r) o[r] = f2bf(acc[mi][ni][r] + bb);
                *(bf16x4*)&vT[(size_t)(bh * 64 + dk) * L_ + l] = o;
            } else {
                short* dst = (z == 0) ? qh : kh;
                const float sc = (z == 0) ? QSCALE : 1.0f;
#pragma unroll
                for (int r = 0; r < 4; ++r)
                    dst[((size_t)bh * L_ + l + r) * DK_ + dk] = f2bf((acc[mi][ni][r] + bb) * sc);
            }
        }
    }
}

// ------------------------------------------------------------ attention pass 1: stats
// Barrier-free, LDS-free. Each warp: 2 q-groups (32 rows) over the full KV range,
// K fragments loaded per-lane from global (L2-resident, XCD-pinned by bh).
__global__ __launch_bounds__(256, 4)
void attn_stats(const short* __restrict__ qh, const short* __restrict__ kh,
                float* __restrict__ mws, float* __restrict__ isws)
{
    const int bid = blockIdx.x;
    const int wg = (bid & 7) * 64 + (bid >> 3);   // 512 blocks; bh-contiguous per XCD
    const int bh = wg >> 4;
    const int q0 = (wg & 15) * 128;
    const int tid = threadIdx.x;
    const int lane = tid & 63;
    const int w = tid >> 6;
    const int l15 = lane & 15, g = lane >> 4;

    const short* kbase = kh + (size_t)bh * (L_ * DK_);

    bf16x8 qf[2][2];
#pragma unroll
    for (int u = 0; u < 2; ++u)
#pragma unroll
        for (int ks = 0; ks < 2; ++ks)
            qf[u][ks] = *(const bf16x8*)&qh[((size_t)bh * L_ + q0 + w * 32 + u * 16 + l15) * DK_ + ks * 32 + g * 8];

    float m[2][4], s[2][4];
#pragma unroll
    for (int u = 0; u < 2; ++u)
#pragma unroll
        for (int r = 0; r < 4; ++r) { m[u][r] = -1e30f; s[u][r] = 0.f; }

    for (int t = 0; t < 32; ++t) {
        const short* kt = kbase + (size_t)t * 64 * DK_;
        bf16x8 kf[4][2];
#pragma unroll
        for (int cc = 0; cc < 4; ++cc)
#pragma unroll
            for (int ks = 0; ks < 2; ++ks)
                kf[cc][ks] = *(const bf16x8*)&kt[(size_t)(cc * 16 + l15) * DK_ + ks * 32 + g * 8];
#pragma unroll
        for (int u = 0; u < 2; ++u) {
            f32x4 sa[4];
#pragma unroll
            for (int cc = 0; cc < 4; ++cc) sa[cc] = (f32x4)0.f;
#pragma unroll
            for (int cc = 0; cc < 4; ++cc)
#pragma unroll
                for (int ks = 0; ks < 2; ++ks)
                    sa[cc] = __builtin_amdgcn_mfma_f32_16x16x32_bf16(qf[u][ks], kf[cc][ks], sa[cc], 0, 0, 0);
#pragma unroll
            for (int r = 0; r < 4; ++r) {
                const float tm = fmaxf(fmaxf(sa[0][r], sa[1][r]), fmaxf(sa[2][r], sa[3][r]));
                const float mn = fmaxf(m[u][r], tm);
                s[u][r] = s[u][r] * exp2f(m[u][r] - mn)
                        + exp2f(sa[0][r] - mn) + exp2f(sa[1][r] - mn)
                        + exp2f(sa[2][r] - mn) + exp2f(sa[3][r] - mn);
                m[u][r] = mn;
            }
        }
    }
    // combine across the 16 lanes of each col-group
#pragma unroll
    for (int mask = 1; mask <= 8; mask <<= 1) {
#pragma unroll
        for (int u = 0; u < 2; ++u)
#pragma unroll
            for (int r = 0; r < 4; ++r) {
                const float mo = __shfl_xor(m[u][r], mask);
                const float so = __shfl_xor(s[u][r], mask);
                const float mn = fmaxf(m[u][r], mo);
                s[u][r] = s[u][r] * exp2f(m[u][r] - mn) + so * exp2f(mo - mn);
                m[u][r] = mn;
            }
    }
    if (l15 == 0) {
#pragma unroll
        for (int u = 0; u < 2; ++u)
#pragma unroll
            for (int r = 0; r < 4; ++r) {
                const int row = bh * L_ + q0 + w * 32 + u * 16 + g * 4 + r;
                mws[row]  = m[u][r];
                isws[row] = 1.0f / s[u][r];
            }
    }
}

// ------------------------------------------------------------ attention pass 2: P store + PV
// Raw s_barrier + counted vmcnt: attn stores and next-tile gloads stay in flight.
__global__ __launch_bounds__(512, 8)
void attn_pv(const short* __restrict__ qh, const short* __restrict__ kh,
             const short* __restrict__ vT,
             const float* __restrict__ mws, const float* __restrict__ isws,
             float* __restrict__ attn, short* __restrict__ ctxTb)
{
    const int bid = blockIdx.x;
    const int wg = (bid & 7) * 128 + (bid >> 3);      // XCD-contiguous
    const int bh = wg >> 5;
    const int q0 = (wg & 31) * 64;

    const int tid = threadIdx.x;
    const int lane = tid & 63;
    const int w = tid >> 6;
    const int wq = w >> 1, wk = w & 1;
    const int l15 = lane & 15, g = lane >> 4;

    __shared__ short Kb0[64 * 64];
    __shared__ short Kb1[64 * 64];
    __shared__ short Vb[64 * 64];
    __shared__ short Psb[64 * 72];

    const short* kbase = kh + (size_t)bh * (L_ * DK_);
    const short* vbase = vT + (size_t)bh * (DK_ * L_);

    const int lr = lane >> 3, ls = lane & 7;
    const int srow = w * 8 + lr;
    const short* kSrc = kbase + (size_t)srow * DK_ + ((ls ^ (srow & 7)) * 8);
    const short* vSrc = vbase + (size_t)srow * L_ + ((ls ^ (srow & 7)) * 8);
    short* kDst0 = &Kb0[w * 512];
    short* kDst1 = &Kb1[w * 512];
    short* vDst  = &Vb[w * 512];

    bf16x8 qf[2];
#pragma unroll
    for (int ks = 0; ks < 2; ++ks)
        qf[ks] = *(const bf16x8*)&qh[((size_t)bh * L_ + q0 + wq * 16 + l15) * DK_ + ks * 32 + g * 8];

    float m[4], inv_s[4];
#pragma unroll
    for (int r = 0; r < 4; ++r) {
        const int row = bh * L_ + q0 + wq * 16 + g * 4 + r;
        m[r] = mws[row];
        inv_s[r] = isws[row];
    }

    int kbOff[2][2], vbOff[4];
#pragma unroll
    for (int cc = 0; cc < 2; ++cc)
#pragma unroll
        for (int ks = 0; ks < 2; ++ks) {
            const int row = wk * 32 + cc * 16 + l15;
            kbOff[cc][ks] = row * 64 + (((ks * 4 + g) ^ (row & 7)) * 8);
        }
#pragma unroll
    for (int nf = 0; nf < 4; ++nf) {
        const int row = nf * 16 + l15;
        vbOff[nf] = row * 64 + (((wk * 4 + g) ^ (row & 7)) * 8);
    }

    f32x4 cacc[4];
#pragma unroll
    for (int nf = 0; nf < 4; ++nf) cacc[nf] = (f32x4)0.f;

    float* attnB = attn + ((size_t)bh * L_ + q0) * L_;

    gload16(kSrc, kDst0);                             // K(0)
    asm volatile("s_waitcnt vmcnt(0)" ::: "memory");
    __builtin_amdgcn_sched_barrier(0);
    __builtin_amdgcn_s_barrier();

    // per-iter vmem issue order: V(t), K(t+1), stores(t)x8
    for (int t = 0; t < 32; ++t) {
        if (t) {
            asm volatile("s_waitcnt vmcnt(8)" ::: "memory");   // K(t) landed; stores keep flying
            __builtin_amdgcn_sched_barrier(0);
            __builtin_amdgcn_s_barrier();
        }
        gload16(vSrc + t * 64, vDst);                           // V(t)
        {
            const int tn = (t < 31) ? t + 1 : t;                // uniform issue count
            gload16(kSrc + (size_t)tn * 64 * DK_, (t & 1) ? kDst0 : kDst1);
        }
        const short* kb = (t & 1) ? Kb1 : Kb0;
        f32x4 sa[2];
#pragma unroll
        for (int cc = 0; cc < 2; ++cc) sa[cc] = (f32x4)0.f;
        __builtin_amdgcn_s_setprio(1);
#pragma unroll
        for (int cc = 0; cc < 2; ++cc)
#pragma unroll
            for (int ks = 0; ks < 2; ++ks)
                sa[cc] = __builtin_amdgcn_mfma_f32_16x16x32_bf16(qf[ks], *(const bf16x8*)&kb[kbOff[cc][ks]], sa[cc], 0, 0, 0);
        __builtin_amdgcn_s_setprio(0);
#pragma unroll
        for (int cc = 0; cc < 2; ++cc)
#pragma unroll
            for (int r = 0; r < 4; ++r) {
                const float p = exp2f(sa[cc][r] - m[r]) * inv_s[r];
                Psb[(wq * 16 + g * 4 + r) * 72 + wk * 32 + cc * 16 + l15] = f2bf(p);
                __builtin_nontemporal_store(
                    p, attnB + (size_t)(wq * 16 + g * 4 + r) * L_ + t * 64 + wk * 32 + cc * 16 + l15);
            }
        // V(t) landed (9 newer: K(t+1)+8 stores), Psb visible
        asm volatile("s_waitcnt vmcnt(9) lgkmcnt(0)" ::: "memory");
        __builtin_amdgcn_sched_barrier(0);
        __builtin_amdgcn_s_barrier();
        const bf16x8 pa = *(const bf16x8*)&Psb[(wq * 16 + l15) * 72 + wk * 32 + g * 8];
        __builtin_amdgcn_s_setprio(1);
#pragma unroll
        for (int nf = 0; nf < 4; ++nf)
            cacc[nf] = __builtin_amdgcn_mfma_f32_16x16x32_bf16(pa, *(const bf16x8*)&Vb[vbOff[nf]], cacc[nf], 0, 0, 0);
        __builtin_amdgcn_s_setprio(0);
    }

    // epilogue: combine kv-halves, store ctx^T bf16
    __syncthreads();
    float* scr = (float*)&Kb0[0];
    float* scr1 = (float*)&Kb1[0];
    if (wk) {
#pragma unroll
        for (int nf = 0; nf < 4; ++nf) {
            float* p = (nf < 2) ? scr : scr1;
            *(f32x4*)&p[(((wq * 2) + (nf & 1)) * 64 + lane) * 4] = cacc[nf];
        }
    }
    __syncthreads();
    if (!wk) {
#pragma unroll
        for (int nf = 0; nf < 4; ++nf) {
            const float* p = (nf < 2) ? scr : scr1;
            const f32x4 o = cacc[nf] + *(const f32x4*)&p[(((wq * 2) + (nf & 1)) * 64 + lane) * 4];
            bf16x4 ob;
#pragma unroll
            for (int r = 0; r < 4; ++r) ob[r] = f2bf(o[r]);
            *(bf16x4*)&ctxTb[(size_t)(bh * 64 + nf * 16 + l15) * L_ + q0 + wq * 16 + g * 4] = ob;
        }
    }
}

// ------------------------------------------------------------ output projection (MFMA, BM=128 BN=64, 2 blocks/CU)
__global__ __launch_bounds__(256)
void out_mfma(const short* __restrict__ ctxTb, const short* __restrict__ xoutb,
              const short* __restrict__ WoT, const float* __restrict__ bo,
              float* __restrict__ out)
{
    const int flat = blockIdx.y * 16 + blockIdx.x;
    const int wgs = (flat & 7) * 64 + (flat >> 3);
    const int col0 = (wgs & 15) * 64;
    const int row0 = (wgs >> 4) * 128;
    const int tid = threadIdx.x;
    const int lane = tid & 63;
    const int w = tid >> 6;
    const int wm = (w >> 1) * 64, wn = (w & 1) * 32;
    const int l15 = lane & 15, g = lane >> 4;
    const int sub = lane >> 3, slt = lane & 7;

    __shared__ short As[128 * 64];
    __shared__ short Bs[64 * 64];

    const short* pA1[4]; const short* pA2[4]; const short* pB[2];
    short* ldsA[4]; short* ldsB[2];
#pragma unroll
    for (int i = 0; i < 4; ++i) {
        const int r = w * 32 + i * 8 + sub;
        const int rr = row0 + r;
        const int b = rr >> 11, l_ = rr & (L_ - 1);
        const int bh = b * 16 + (l_ >> 7), d = (l_ & 127) >> 1;
        const size_t off1 = ((size_t)(bh * 64 + d) << 11) + (size_t)((l_ & 1) << 10);
        const int sc = ((slt ^ (r & 7)) * 8);
        pA1[i] = ctxTb + off1 + sc;
        pA2[i] = xoutb + (size_t)rr * DIM_ + sc;
        ldsA[i] = &As[(w * 32 + i * 8) * 64];
    }
#pragma unroll
    for (int i = 0; i < 2; ++i) {
        const int r = w * 16 + i * 8 + sub;
        const int sc = ((slt ^ (r & 7)) * 8);
        pB[i]  = WoT + (size_t)(col0 + r) * (2 * DIM_) + sc;
        ldsB[i] = &Bs[(w * 16 + i * 8) * 64];
    }

    f32x4 acc[4][2];
#pragma unroll
    for (int mi = 0; mi < 4; ++mi)
#pragma unroll
        for (int ni = 0; ni < 2; ++ni) acc[mi][ni] = (f32x4)0.f;

    for (int k0 = 0; k0 < 2 * DIM_; k0 += 64) {
        const bool first = (k0 < DIM_);
        const int kk = first ? k0 : k0 - DIM_;
#pragma unroll
        for (int i = 0; i < 4; ++i)
            gload16(first ? (pA1[i] + kk) : (pA2[i] + kk), ldsA[i]);
#pragma unroll
        for (int i = 0; i < 2; ++i)
            gload16(pB[i] + k0, ldsB[i]);
        __syncthreads();
        bf16x8 af[4][2], bfr[2][2];
#pragma unroll
        for (int mi = 0; mi < 4; ++mi) {
            const int wa = wm + mi * 16 + l15;
#pragma unroll
            for (int ks = 0; ks < 2; ++ks)
                af[mi][ks] = *(const bf16x8*)&As[wa * 64 + (((ks * 4 + g) ^ (wa & 7)) * 8)];
        }
#pragma unroll
        for (int ni = 0; ni < 2; ++ni) {
            const int wb = wn + ni * 16 + l15;
#pragma unroll
            for (int ks = 0; ks < 2; ++ks)
                bfr[ni][ks] = *(const bf16x8*)&Bs[wb * 64 + (((ks * 4 + g) ^ (wb & 7)) * 8)];
        }
        __builtin_amdgcn_s_setprio(1);
#pragma unroll
        for (int mi = 0; mi < 4; ++mi)
#pragma unroll
            for (int ni = 0; ni < 2; ++ni)
#pragma unroll
                for (int ks = 0; ks < 2; ++ks)
                    acc[mi][ni] = __builtin_amdgcn_mfma_f32_16x16x32_bf16(af[mi][ks], bfr[ni][ks], acc[mi][ni], 0, 0, 0);
        __builtin_amdgcn_s_setprio(0);
        __syncthreads();
    }

#pragma unroll
    for (int ni = 0; ni < 2; ++ni) {
        const int col = col0 + wn + ni * 16 + l15;
        const float bb = bo[col];
#pragma unroll
        for (int mi = 0; mi < 4; ++mi) {
            const int rowb = row0 + wm + mi * 16 + g * 4;
#pragma unroll
            for (int r = 0; r < 4; ++r)
                out[(size_t)(rowb + r) * DIM_ + col] = tanhf(acc[mi][ni][r] + bb);
        }
    }
}

// ------------------------------------------------------------ launch
extern "C" void kernel_launch(void* const* d_in, const int* in_sizes, int n_in,
                              void* d_out, int out_size, void* d_ws, size_t ws_size,
                              hipStream_t stream)
{
    const float* xout = (const float*)d_in[0];
    const float* xctx = (const float*)d_in[1];
    const float* Wq = (const float*)d_in[2];
    const float* bq = (const float*)d_in[3];
    const float* Wk = (const float*)d_in[4];
    const float* bk = (const float*)d_in[5];
    const float* Wv = (const float*)d_in[6];
    const float* bv = (const float*)d_in[7];
    const float* Wo = (const float*)d_in[8];
    const float* bo = (const float*)d_in[9];

    float* out  = (float*)d_out;
    float* attn = out + (size_t)M_ * DIM_;

    short* ws = (short*)d_ws;
    short* xoutb = ws;
    short* xctxb = xoutb + (size_t)M_ * DIM_;
    short* WqT   = xctxb + (size_t)M_ * DIM_;
    short* WkT   = WqT + (size_t)DIM_ * DIM_;
    short* WvT   = WkT + (size_t)DIM_ * DIM_;
    short* WoT   = WvT + (size_t)DIM_ * DIM_;
    short* qh    = WoT + (size_t)2 * DIM_ * DIM_;
    short* kh    = qh + (size_t)BH_ * L_ * DK_;
    short* vT    = kh + (size_t)BH_ * L_ * DK_;
    short* ctxTb = vT + (size_t)BH_ * L_ * DK_;
    float* mws   = (float*)(ctxTb + (size_t)BH_ * L_ * DK_);   // [BH*L]
    float* isws  = mws + (size_t)BH_ * L_;                     // [BH*L]

    cvt_bf16<<<(2 * M_ * DIM_ / 8) / 256, 256, 0, stream>>>(xout, xctx, xoutb, xctxb);
    wtrans<<<dim3(32, 16, 4), 256, 0, stream>>>(Wq, Wk, Wv, Wo, WqT, WkT, WvT, WoT);
    qkv_mfma<<<dim3(8, 32, 3), 256, 0, stream>>>(
        xoutb, xctxb, WqT, WkT, WvT, bq, bk, bv, qh, kh, vT);
    attn_stats<<<512, 256, 0, stream>>>(qh, kh, mws, isws);
    attn_pv<<<1024, 512, 0, stream>>>(qh, kh, vT, mws, isws, attn, ctxTb);
    out_mfma<<<dim3(16, 32), 256, 0, stream>>>(ctxTb, xoutb, WoT, bo, out);
}

// Round 8
// 279.181 us; speedup vs baseline: 1.2325x; 1.2325x over previous
//
#include <hip/hip_runtime.h>
#include <math.h>
#include <stdint.h>

#define DIM_ 1024
#define HEADS_ 16
#define DK_ 64
#define B_ 2
#define L_ 2048
#define BH_ (B_*HEADS_)
#define M_ (B_*L_)

typedef __attribute__((ext_vector_type(4))) float f32x4;
typedef __attribute__((ext_vector_type(8))) short bf16x8;
typedef __attribute__((ext_vector_type(4))) short bf16x4;

#define QSCALE 0.18033688f   // 0.125 * log2(e): softmax in exp2 domain

static __device__ __forceinline__ short f2bf(float f) {
    uint32_t u = __builtin_bit_cast(uint32_t, f);
    u += 0x7fffu + ((u >> 16) & 1u);
    return (short)(u >> 16);
}
static __device__ __forceinline__ void gload16(const void* g, void* l) {
    __builtin_amdgcn_global_load_lds(
        (const __attribute__((address_space(1))) unsigned int*)g,
        (__attribute__((address_space(3))) unsigned int*)l, 16, 0, 0);
}

// ------------------------------------------------------------ prep (fused): fp32->bf16 cvt + W transpose
__global__ __launch_bounds__(256)
void prep(const float* __restrict__ xout, const float* __restrict__ xctx,
          const float* __restrict__ Wq, const float* __restrict__ Wk,
          const float* __restrict__ Wv, const float* __restrict__ Wo,
          short* __restrict__ xoutb, short* __restrict__ xctxb,
          short* __restrict__ WqT, short* __restrict__ WkT,
          short* __restrict__ WvT, short* __restrict__ WoT)
{
    __shared__ float ts[64][65];
    const int bid = blockIdx.x;
    const int tid = threadIdx.x;
    if (bid < 4096) {
        // cvt: 4096 blocks x 256 thr x 8 elems = 2*M*DIM
        const int id = bid * 256 + tid;
        const int nA = (M_ * DIM_) / 8;
        const float* src = (id < nA) ? xout : xctx;
        short* dst = (id < nA) ? xoutb : xctxb;
        const int c = (id < nA) ? id : id - nA;
        const f32x4 v0 = *(const f32x4*)&src[(size_t)c * 8];
        const f32x4 v1 = *(const f32x4*)&src[(size_t)c * 8 + 4];
        bf16x8 o;
#pragma unroll
        for (int i = 0; i < 4; ++i) { o[i] = f2bf(v0[i]); o[4 + i] = f2bf(v1[i]); }
        *(bf16x8*)&dst[(size_t)c * 8] = o;
        return;
    }
    // wtrans: 2048 blocks = 4 z x (32 x 16)
    const int flat = bid - 4096;
    const int z = flat >> 9;
    const int rem = flat & 511;
    const int K = (z == 3) ? 2 * DIM_ : DIM_;
    const int k0 = (rem & 31) * 64;
    if (k0 >= K) return;
    const int n0 = (rem >> 5) * 64;
    const float* W = (z == 0) ? Wq : (z == 1) ? Wk : (z == 2) ? Wv : Wo;
    short* WT = (z == 0) ? WqT : (z == 1) ? WkT : (z == 2) ? WvT : WoT;
    {
        const int k = tid >> 2, noff = (tid & 3) * 16;
#pragma unroll
        for (int i = 0; i < 4; ++i)
            *(f32x4*)&ts[k][noff + i * 4] =
                *(const f32x4*)&W[(size_t)(k0 + k) * DIM_ + n0 + noff + i * 4];
    }
    __syncthreads();
    {
        const int n = tid >> 2, koff = (tid & 3) * 16;
#pragma unroll
        for (int c = 0; c < 2; ++c) {
            bf16x8 o;
#pragma unroll
            for (int i = 0; i < 8; ++i) o[i] = f2bf(ts[koff + c * 8 + i][n]);
            *(bf16x8*)&WT[(size_t)(n0 + n) * K + k0 + koff + c * 8] = o;
        }
    }
}

// ------------------------------------------------------------ QKV GEMM (MFMA, gload_lds, BK=64, XOR-swizzled LDS)
__global__ __launch_bounds__(256)
void qkv_mfma(const short* __restrict__ xoutb, const short* __restrict__ xctxb,
              const short* __restrict__ WqT, const short* __restrict__ WkT,
              const short* __restrict__ WvT,
              const float* __restrict__ bq, const float* __restrict__ bk,
              const float* __restrict__ bv,
              short* __restrict__ qh, short* __restrict__ kh, short* __restrict__ vT)
{
    const int z = blockIdx.z;
    const short* A  = (z == 0) ? xoutb : xctxb;
    const short* Bt = (z == 0) ? WqT : (z == 1) ? WkT : WvT;
    const float* bias = (z == 0) ? bq : (z == 1) ? bk : bv;

    const int flat = blockIdx.y * 8 + blockIdx.x;
    const int wgs = (flat & 7) * 32 + (flat >> 3);
    const int col0 = (wgs & 7) * 128;
    const int row0 = (wgs >> 3) * 128;
    const int tid = threadIdx.x;
    const int lane = tid & 63;
    const int w = tid >> 6;
    const int wm = (w >> 1) * 64, wn = (w & 1) * 64;
    const int l15 = lane & 15, g = lane >> 4;
    const int sub = lane >> 3, slt = lane & 7;

    __shared__ short As[128 * 64];
    __shared__ short Bs[128 * 64];

    const short* pA[4]; const short* pB[4]; short* ldsA[4]; short* ldsB[4];
#pragma unroll
    for (int i = 0; i < 4; ++i) {
        const int r = w * 32 + i * 8 + sub;
        const int sc = ((slt ^ (r & 7)) * 8);
        pA[i] = A  + (size_t)(row0 + r) * DIM_ + sc;
        pB[i] = Bt + (size_t)(col0 + r) * DIM_ + sc;
        ldsA[i] = &As[(w * 32 + i * 8) * 64];
        ldsB[i] = &Bs[(w * 32 + i * 8) * 64];
    }

    f32x4 acc[4][4];
#pragma unroll
    for (int mi = 0; mi < 4; ++mi)
#pragma unroll
        for (int ni = 0; ni < 4; ++ni) acc[mi][ni] = (f32x4)0.f;

    for (int k0 = 0; k0 < DIM_; k0 += 64) {
#pragma unroll
        for (int i = 0; i < 4; ++i) {
            gload16(pA[i] + k0, ldsA[i]);
            gload16(pB[i] + k0, ldsB[i]);
        }
        __syncthreads();
        bf16x8 af[4][2], bfr[4][2];
#pragma unroll
        for (int mi = 0; mi < 4; ++mi) {
            const int wa = wm + mi * 16 + l15;
#pragma unroll
            for (int ks = 0; ks < 2; ++ks)
                af[mi][ks] = *(const bf16x8*)&As[wa * 64 + (((ks * 4 + g) ^ (wa & 7)) * 8)];
        }
#pragma unroll
        for (int ni = 0; ni < 4; ++ni) {
            const int wb = wn + ni * 16 + l15;
#pragma unroll
            for (int ks = 0; ks < 2; ++ks)
                bfr[ni][ks] = *(const bf16x8*)&Bs[wb * 64 + (((ks * 4 + g) ^ (wb & 7)) * 8)];
        }
        __builtin_amdgcn_s_setprio(1);
#pragma unroll
        for (int mi = 0; mi < 4; ++mi)
#pragma unroll
            for (int ni = 0; ni < 4; ++ni)
#pragma unroll
                for (int ks = 0; ks < 2; ++ks)
                    acc[mi][ni] = __builtin_amdgcn_mfma_f32_16x16x32_bf16(af[mi][ks], bfr[ni][ks], acc[mi][ni], 0, 0, 0);
        __builtin_amdgcn_s_setprio(0);
        __syncthreads();
    }

#pragma unroll
    for (int ni = 0; ni < 4; ++ni) {
        const int col = col0 + wn + ni * 16 + l15;
        const int h = col >> 6, dk = col & 63;
        const float bb = bias[col];
#pragma unroll
        for (int mi = 0; mi < 4; ++mi) {
            const int rowb = row0 + wm + mi * 16 + g * 4;
            const int b = rowb >> 11;
            const int l = rowb & (L_ - 1);
            const int bh = b * 16 + h;
            if (z == 2) {
                bf16x4 o;
#pragma unroll
                for (int r = 0; r < 4; ++r) o[r] = f2bf(acc[mi][ni][r] + bb);
                *(bf16x4*)&vT[(size_t)(bh * 64 + dk) * L_ + l] = o;
            } else {
                short* dst = (z == 0) ? qh : kh;
                const float sc = (z == 0) ? QSCALE : 1.0f;
#pragma unroll
                for (int r = 0; r < 4; ++r)
                    dst[((size_t)bh * L_ + l + r) * DK_ + dk] = f2bf((acc[mi][ni][r] + bb) * sc);
            }
        }
    }
}

// ------------------------------------------------------------ fused attention v6
// Monolithic (round-6 structure). Pass 1: 4-deep K pipeline (Vb/Psb aliased as
// K buffers, counted vmcnt(2)). Pass 2: counted-vmcnt stores/loads (round 6).
__global__ __launch_bounds__(512, 8)
void attn_mfma(const short* __restrict__ qh, const short* __restrict__ kh,
               const short* __restrict__ vT,
               float* __restrict__ attn, short* __restrict__ ctxTb)
{
    const int bid = blockIdx.x;
    const int wg = (bid & 7) * 128 + (bid >> 3);      // XCD-contiguous
    const int bh = wg >> 5;
    const int q0 = (wg & 31) * 64;

    const int tid = threadIdx.x;
    const int lane = tid & 63;
    const int w = tid >> 6;
    const int wq = w >> 1, wk = w & 1;
    const int l15 = lane & 15, g = lane >> 4;

    // one arena: [0..4k)=Kb0, [4k..8k)=Kb1, [8k..12k)=Vb, [12288..16896)=Psb, then stat
    __shared__ short SM[17408];
    short* const Kb0 = SM;
    short* const Kb1 = SM + 4096;
    short* const Vb  = SM + 8192;
    short* const Psb = SM + 12288;                    // 64 x 72
    float* const stat = (float*)(SM + 16896);         // [4][2][16][2]

    const short* kbase = kh + (size_t)bh * (L_ * DK_);
    const short* vbase = vT + (size_t)bh * (DK_ * L_);

    const int lr = lane >> 3, ls = lane & 7;
    const int srow = w * 8 + lr;
    const short* kSrc = kbase + (size_t)srow * DK_ + ((ls ^ (srow & 7)) * 8);
    const short* vSrc = vbase + (size_t)srow * L_ + ((ls ^ (srow & 7)) * 8);

    bf16x8 qf[2];
#pragma unroll
    for (int ks = 0; ks < 2; ++ks)
        qf[ks] = *(const bf16x8*)&qh[((size_t)bh * L_ + q0 + wq * 16 + l15) * DK_ + ks * 32 + g * 8];

    int kbOff[2][2], vbOff[4];
#pragma unroll
    for (int cc = 0; cc < 2; ++cc)
#pragma unroll
        for (int ks = 0; ks < 2; ++ks) {
            const int row = wk * 32 + cc * 16 + l15;
            kbOff[cc][ks] = row * 64 + (((ks * 4 + g) ^ (row & 7)) * 8);
        }
#pragma unroll
    for (int nf = 0; nf < 4; ++nf) {
        const int row = nf * 16 + l15;
        vbOff[nf] = row * 64 + (((wk * 4 + g) ^ (row & 7)) * 8);
    }

    // ---------------- pass 1: online stats, 4-deep K pipeline
    float m[4], s[4];
#pragma unroll
    for (int r = 0; r < 4; ++r) { m[r] = -1e30f; s[r] = 0.f; }

#pragma unroll
    for (int i = 0; i < 3; ++i)
        gload16(kSrc + (size_t)i * 64 * DK_, SM + (i << 12) + w * 512);
    asm volatile("s_waitcnt vmcnt(2)" ::: "memory");   // K(0) landed
    __builtin_amdgcn_sched_barrier(0);
    __builtin_amdgcn_s_barrier();

    for (int t = 0; t < 32; ++t) {
        if (t < 29)
            gload16(kSrc + (size_t)(t + 3) * 64 * DK_, SM + (((t + 3) & 3) << 12) + w * 512);
        const short* kb = SM + ((t & 3) << 12);
        f32x4 sa[2];
#pragma unroll
        for (int cc = 0; cc < 2; ++cc) sa[cc] = (f32x4)0.f;
        __builtin_amdgcn_s_setprio(1);
#pragma unroll
        for (int cc = 0; cc < 2; ++cc)
#pragma unroll
            for (int ks = 0; ks < 2; ++ks)
                sa[cc] = __builtin_amdgcn_mfma_f32_16x16x32_bf16(qf[ks], *(const bf16x8*)&kb[kbOff[cc][ks]], sa[cc], 0, 0, 0);
        __builtin_amdgcn_s_setprio(0);
#pragma unroll
        for (int r = 0; r < 4; ++r) {
            const float tm = fmaxf(sa[0][r], sa[1][r]);
            const float mn = fmaxf(m[r], tm);
            s[r] = s[r] * exp2f(m[r] - mn) + exp2f(sa[0][r] - mn) + exp2f(sa[1][r] - mn);
            m[r] = mn;
        }
        // K(t+1) landed: counted wait (exact tail counts, no dummy issues)
        if (t < 29)       { asm volatile("s_waitcnt vmcnt(2)" ::: "memory"); }
        else if (t == 29) { asm volatile("s_waitcnt vmcnt(1)" ::: "memory"); }
        else if (t == 30) { asm volatile("s_waitcnt vmcnt(0)" ::: "memory"); }
        __builtin_amdgcn_sched_barrier(0);
        if (t < 31) __builtin_amdgcn_s_barrier();
    }
#pragma unroll
    for (int mask = 1; mask <= 8; mask <<= 1) {
#pragma unroll
        for (int r = 0; r < 4; ++r) {
            const float mo = __shfl_xor(m[r], mask);
            const float so = __shfl_xor(s[r], mask);
            const float mn = fmaxf(m[r], mo);
            s[r] = s[r] * exp2f(m[r] - mn) + so * exp2f(mo - mn);
            m[r] = mn;
        }
    }
    if (l15 == 0) {
#pragma unroll
        for (int r = 0; r < 4; ++r) {
            stat[((wq * 2 + wk) * 16 + g * 4 + r) * 2 + 0] = m[r];
            stat[((wq * 2 + wk) * 16 + g * 4 + r) * 2 + 1] = s[r];
        }
    }
    gload16(kSrc, SM + w * 512);                       // K(0) for pass 2 -> Kb0
    asm volatile("s_waitcnt lgkmcnt(0)" ::: "memory"); // stat visible
    __builtin_amdgcn_s_barrier();
    float inv_s[4];
#pragma unroll
    for (int r = 0; r < 4; ++r) {
        const float m0 = stat[((wq * 2 + 0) * 16 + g * 4 + r) * 2 + 0];
        const float s0 = stat[((wq * 2 + 0) * 16 + g * 4 + r) * 2 + 1];
        const float m1 = stat[((wq * 2 + 1) * 16 + g * 4 + r) * 2 + 0];
        const float s1 = stat[((wq * 2 + 1) * 16 + g * 4 + r) * 2 + 1];
        const float mn = fmaxf(m0, m1);
        m[r] = mn;
        inv_s[r] = 1.0f / (s0 * exp2f(m0 - mn) + s1 * exp2f(m1 - mn));
    }

    f32x4 cacc[4];
#pragma unroll
    for (int nf = 0; nf < 4; ++nf) cacc[nf] = (f32x4)0.f;

    float* attnB = attn + ((size_t)bh * L_ + q0) * L_;

    asm volatile("s_waitcnt vmcnt(0)" ::: "memory");   // K(0) landed
    __builtin_amdgcn_sched_barrier(0);
    __builtin_amdgcn_s_barrier();

    // ---------------- pass 2: recompute, fp32 register attn stores, PV
    // per-iter vmem issue order: V(t), K(t+1), stores(t)x8
    for (int t = 0; t < 32; ++t) {
        if (t) {
            asm volatile("s_waitcnt vmcnt(8)" ::: "memory");   // K(t) landed; stores keep flying
            __builtin_amdgcn_sched_barrier(0);
            __builtin_amdgcn_s_barrier();
        }
        gload16(vSrc + t * 64, Vb + w * 512);                   // V(t)
        {
            const int tn = (t < 31) ? t + 1 : t;                // uniform issue count
            gload16(kSrc + (size_t)tn * 64 * DK_, ((t & 1) ? Kb0 : Kb1) + w * 512);
        }
        const short* kb = (t & 1) ? Kb1 : Kb0;
        f32x4 sa[2];
#pragma unroll
        for (int cc = 0; cc < 2; ++cc) sa[cc] = (f32x4)0.f;
        __builtin_amdgcn_s_setprio(1);
#pragma unroll
        for (int cc = 0; cc < 2; ++cc)
#pragma unroll
            for (int ks = 0; ks < 2; ++ks)
                sa[cc] = __builtin_amdgcn_mfma_f32_16x16x32_bf16(qf[ks], *(const bf16x8*)&kb[kbOff[cc][ks]], sa[cc], 0, 0, 0);
        __builtin_amdgcn_s_setprio(0);
#pragma unroll
        for (int cc = 0; cc < 2; ++cc)
#pragma unroll
            for (int r = 0; r < 4; ++r) {
                const float p = exp2f(sa[cc][r] - m[r]) * inv_s[r];
                Psb[(wq * 16 + g * 4 + r) * 72 + wk * 32 + cc * 16 + l15] = f2bf(p);
                __builtin_nontemporal_store(
                    p, attnB + (size_t)(wq * 16 + g * 4 + r) * L_ + t * 64 + wk * 32 + cc * 16 + l15);
            }
        // V(t) landed (9 newer: K(t+1)+8 stores), Psb visible
        asm volatile("s_waitcnt vmcnt(9) lgkmcnt(0)" ::: "memory");
        __builtin_amdgcn_sched_barrier(0);
        __builtin_amdgcn_s_barrier();
        const bf16x8 pa = *(const bf16x8*)&Psb[(wq * 16 + l15) * 72 + wk * 32 + g * 8];
        __builtin_amdgcn_s_setprio(1);
#pragma unroll
        for (int nf = 0; nf < 4; ++nf)
            cacc[nf] = __builtin_amdgcn_mfma_f32_16x16x32_bf16(pa, *(const bf16x8*)&Vb[vbOff[nf]], cacc[nf], 0, 0, 0);
        __builtin_amdgcn_s_setprio(0);
    }

    // epilogue: combine kv-halves, store ctx^T bf16
    __syncthreads();
    float* scr = (float*)Kb0;
    float* scr1 = (float*)Kb1;
    if (wk) {
#pragma unroll
        for (int nf = 0; nf < 4; ++nf) {
            float* p = (nf < 2) ? scr : scr1;
            *(f32x4*)&p[(((wq * 2) + (nf & 1)) * 64 + lane) * 4] = cacc[nf];
        }
    }
    __syncthreads();
    if (!wk) {
#pragma unroll
        for (int nf = 0; nf < 4; ++nf) {
            const float* p = (nf < 2) ? scr : scr1;
            const f32x4 o = cacc[nf] + *(const f32x4*)&p[(((wq * 2) + (nf & 1)) * 64 + lane) * 4];
            bf16x4 ob;
#pragma unroll
            for (int r = 0; r < 4; ++r) ob[r] = f2bf(o[r]);
            *(bf16x4*)&ctxTb[(size_t)(bh * 64 + nf * 16 + l15) * L_ + q0 + wq * 16 + g * 4] = ob;
        }
    }
}

// ------------------------------------------------------------ output projection (MFMA, BM=128 BN=64, 2 blocks/CU)
__global__ __launch_bounds__(256)
void out_mfma(const short* __restrict__ ctxTb, const short* __restrict__ xoutb,
              const short* __restrict__ WoT, const float* __restrict__ bo,
              float* __restrict__ out)
{
    const int flat = blockIdx.y * 16 + blockIdx.x;
    const int wgs = (flat & 7) * 64 + (flat >> 3);
    const int col0 = (wgs & 15) * 64;
    const int row0 = (wgs >> 4) * 128;
    const int tid = threadIdx.x;
    const int lane = tid & 63;
    const int w = tid >> 6;
    const int wm = (w >> 1) * 64, wn = (w & 1) * 32;
    const int l15 = lane & 15, g = lane >> 4;
    const int sub = lane >> 3, slt = lane & 7;

    __shared__ short As[128 * 64];
    __shared__ short Bs[64 * 64];

    const short* pA1[4]; const short* pA2[4]; const short* pB[2];
    short* ldsA[4]; short* ldsB[2];
#pragma unroll
    for (int i = 0; i < 4; ++i) {
        const int r = w * 32 + i * 8 + sub;
        const int rr = row0 + r;
        const int b = rr >> 11, l_ = rr & (L_ - 1);
        const int bh = b * 16 + (l_ >> 7), d = (l_ & 127) >> 1;
        const size_t off1 = ((size_t)(bh * 64 + d) << 11) + (size_t)((l_ & 1) << 10);
        const int sc = ((slt ^ (r & 7)) * 8);
        pA1[i] = ctxTb + off1 + sc;
        pA2[i] = xoutb + (size_t)rr * DIM_ + sc;
        ldsA[i] = &As[(w * 32 + i * 8) * 64];
    }
#pragma unroll
    for (int i = 0; i < 2; ++i) {
        const int r = w * 16 + i * 8 + sub;
        const int sc = ((slt ^ (r & 7)) * 8);
        pB[i]  = WoT + (size_t)(col0 + r) * (2 * DIM_) + sc;
        ldsB[i] = &Bs[(w * 16 + i * 8) * 64];
    }

    f32x4 acc[4][2];
#pragma unroll
    for (int mi = 0; mi < 4; ++mi)
#pragma unroll
        for (int ni = 0; ni < 2; ++ni) acc[mi][ni] = (f32x4)0.f;

    for (int k0 = 0; k0 < 2 * DIM_; k0 += 64) {
        const bool first = (k0 < DIM_);
        const int kk = first ? k0 : k0 - DIM_;
#pragma unroll
        for (int i = 0; i < 4; ++i)
            gload16(first ? (pA1[i] + kk) : (pA2[i] + kk), ldsA[i]);
#pragma unroll
        for (int i = 0; i < 2; ++i)
            gload16(pB[i] + k0, ldsB[i]);
        __syncthreads();
        bf16x8 af[4][2], bfr[2][2];
#pragma unroll
        for (int mi = 0; mi < 4; ++mi) {
            const int wa = wm + mi * 16 + l15;
#pragma unroll
            for (int ks = 0; ks < 2; ++ks)
                af[mi][ks] = *(const bf16x8*)&As[wa * 64 + (((ks * 4 + g) ^ (wa & 7)) * 8)];
        }
#pragma unroll
        for (int ni = 0; ni < 2; ++ni) {
            const int wb = wn + ni * 16 + l15;
#pragma unroll
            for (int ks = 0; ks < 2; ++ks)
                bfr[ni][ks] = *(const bf16x8*)&Bs[wb * 64 + (((ks * 4 + g) ^ (wb & 7)) * 8)];
        }
        __builtin_amdgcn_s_setprio(1);
#pragma unroll
        for (int mi = 0; mi < 4; ++mi)
#pragma unroll
            for (int ni = 0; ni < 2; ++ni)
#pragma unroll
                for (int ks = 0; ks < 2; ++ks)
                    acc[mi][ni] = __builtin_amdgcn_mfma_f32_16x16x32_bf16(af[mi][ks], bfr[ni][ks], acc[mi][ni], 0, 0, 0);
        __builtin_amdgcn_s_setprio(0);
        __syncthreads();
    }

#pragma unroll
    for (int ni = 0; ni < 2; ++ni) {
        const int col = col0 + wn + ni * 16 + l15;
        const float bb = bo[col];
#pragma unroll
        for (int mi = 0; mi < 4; ++mi) {
            const int rowb = row0 + wm + mi * 16 + g * 4;
#pragma unroll
            for (int r = 0; r < 4; ++r)
                out[(size_t)(rowb + r) * DIM_ + col] = tanhf(acc[mi][ni][r] + bb);
        }
    }
}

// ------------------------------------------------------------ launch
extern "C" void kernel_launch(void* const* d_in, const int* in_sizes, int n_in,
                              void* d_out, int out_size, void* d_ws, size_t ws_size,
                              hipStream_t stream)
{
    const float* xout = (const float*)d_in[0];
    const float* xctx = (const float*)d_in[1];
    const float* Wq = (const float*)d_in[2];
    const float* bq = (const float*)d_in[3];
    const float* Wk = (const float*)d_in[4];
    const float* bk = (const float*)d_in[5];
    const float* Wv = (const float*)d_in[6];
    const float* bv = (const float*)d_in[7];
    const float* Wo = (const float*)d_in[8];
    const float* bo = (const float*)d_in[9];

    float* out  = (float*)d_out;
    float* attn = out + (size_t)M_ * DIM_;

    short* ws = (short*)d_ws;
    short* xoutb = ws;
    short* xctxb = xoutb + (size_t)M_ * DIM_;
    short* WqT   = xctxb + (size_t)M_ * DIM_;
    short* WkT   = WqT + (size_t)DIM_ * DIM_;
    short* WvT   = WkT + (size_t)DIM_ * DIM_;
    short* WoT   = WvT + (size_t)DIM_ * DIM_;
    short* qh    = WoT + (size_t)2 * DIM_ * DIM_;
    short* kh    = qh + (size_t)BH_ * L_ * DK_;
    short* vT    = kh + (size_t)BH_ * L_ * DK_;
    short* ctxTb = vT + (size_t)BH_ * L_ * DK_;

    prep<<<6144, 256, 0, stream>>>(xout, xctx, Wq, Wk, Wv, Wo,
                                   xoutb, xctxb, WqT, WkT, WvT, WoT);
    qkv_mfma<<<dim3(8, 32, 3), 256, 0, stream>>>(
        xoutb, xctxb, WqT, WkT, WvT, bq, bk, bv, qh, kh, vT);
    attn_mfma<<<1024, 512, 0, stream>>>(qh, kh, vT, attn, ctxTb);
    out_mfma<<<dim3(16, 32), 256, 0, stream>>>(ctxTb, xoutb, WoT, bo, out);
}